// Round 4
// baseline (276.322 us; speedup 1.0000x reference)
//
#include <hip/hip_runtime.h>
#include <math.h>

// SpectralConv3d via DHT identities:
//   r = Re(F) - Im(G);  ||r||^2 = (N^3/2)(2*sum x^2 + c1 - c2)  [cross term = 0]
//   corner: n3->k3 + n2->k2 fused (k_fwd1, cos/sin-folded, table twiddles),
//           n1->k1 (k_fwd2s)
//   mix: conv = 0.5*sum_i[(x+xn)w + (x-xn)wn];  ||Y||^2 = (N^3/2)(2*sum conv^2 + conv000^2)
//   expand: n1->k1 (A1), n2->k2 (B2, LDS), n3->k3 with C1/C2 fused flip term.

constexpr int NT = 262144;  // 64^3
constexpr float TWOPI_64 = 0.09817477042468103f;  // 2*pi/64

// ws float offsets:
//   S     [128][64][2][64][2] : 2097152 at 0        (8.4 MB)
//   red1p [128][33][3]        : 12672   at 2097152
//   xh    [128][512]          : 65536   at 2109824
//   inv2  [128]               : 128     at 2175360
//   A1    [128][8192]         : 1048576 at 2175488  (total ~12.9 MB)

// ---------------- K1: folded stage1 (n3->k3) + folded stage2 (n2->k2) + norms ----------
// Fold identity (real row x[0..63], bins k=0..7):
//   re[k] = x[0] + (-1)^k x[32] + sum_{m=1..31} (x[m]+x[64-m]) cos(2pi k m/64)
//   im[k] = -sum_{m=1..31} (x[m]-x[64-m]) sin(2pi k m/64)
__global__ __launch_bounds__(256) void k_fwd1(const float* __restrict__ x,
                                              float* __restrict__ S,
                                              float* __restrict__ red1p) {
  __shared__ float Raw[128 * 71];   // rows 0..63 = A (n1a slab), 64..127 = B; pad 71
  __shared__ float4 F1h[33 * 32];   // [m][n2'] = (uA,vA,uB,vB); half of n2 at a time
  __shared__ float PL[32 * 65];     // stage1 out: rr = rowAB*16 + f*8 + k3, col n2
  __shared__ float2 ct64[64];       // (cos,sin)(2pi j/64)
  __shared__ float rsm[12];
  float2* F2 = (float2*)F1h;        // fold2 output [m][rr], aliases F1h (dead by then)

  const int t = threadIdx.x;
  const int j = blockIdx.x;       // 0..32
  const int bc = blockIdx.y;      // 0..127
  const int n1a = j, n1b = (64 - j) & 63;
  const bool paired = (n1a != n1b);
  if (t < 64) { float ang = TWOPI_64 * t; ct64[t] = make_float2(cosf(ang), sinf(ang)); }

  // ---- P0: load both rows + sum(x^2) partial ----
  const float4* xa4 = (const float4*)(x + ((size_t)bc << 18) + (n1a << 12));
  const float4* xb4 = (const float4*)(x + ((size_t)bc << 18) + (n1b << 12));
  float ssp = 0.f;
  for (int q = 0; q < 4; ++q) {
    int l4 = t + (q << 8);
    int fl = l4 << 2;
    int r = fl >> 6, c = fl & 63;
    float4 va = xa4[l4], vb = xb4[l4];
    Raw[r * 71 + c] = va.x; Raw[r * 71 + c + 1] = va.y;
    Raw[r * 71 + c + 2] = va.z; Raw[r * 71 + c + 3] = va.w;
    Raw[(64 + r) * 71 + c] = vb.x; Raw[(64 + r) * 71 + c + 1] = vb.y;
    Raw[(64 + r) * 71 + c + 2] = vb.z; Raw[(64 + r) * 71 + c + 3] = vb.w;
    ssp += va.x * va.x + va.y * va.y + va.z * va.z + va.w * va.w;
    if (paired) ssp += vb.x * vb.x + vb.y * vb.y + vb.z * vb.z + vb.w * vb.w;
  }
  __syncthreads();

  // ---- P1: fold1(half 0) + norm partials c1,c2 ----
  {
    const int n2p = t & 31, g = t >> 5;
    const int n2 = n2p;  // half 0
#pragma unroll
    for (int e = 0; e < 4; ++e) {
      int m = g * 4 + e;
      if (m == 0) {
        F1h[n2p] = make_float4(Raw[n2 * 71], Raw[n2 * 71 + 32],
                               Raw[(64 + n2) * 71], Raw[(64 + n2) * 71 + 32]);
      } else {
        float a1 = Raw[n2 * 71 + m], a2 = Raw[n2 * 71 + 64 - m];
        float b1 = Raw[(64 + n2) * 71 + m], b2 = Raw[(64 + n2) * 71 + 64 - m];
        F1h[m * 32 + n2p] = make_float4(a1 + a2, a1 - a2, b1 + b2, b1 - b2);
      }
    }
  }
  float c1p = 0.f, c2p = 0.f;
  for (int q = 0; q < 16; ++q) {
    int l = t + (q << 8);
    int r = l >> 6, c = l & 63;
    float a = Raw[r * 71 + c];
    int m2 = (64 - r) & 63;
    int m3 = (64 - c) & 63;
    int m3b = (62 - c) & 63;
    c1p += a * Raw[(64 + m2) * 71 + m3];
    c2p += a * Raw[(64 + m2) * 71 + m3b];
  }
  if (paired) { c1p *= 2.f; c2p *= 2.f; }
  for (int off = 32; off; off >>= 1) {
    ssp += __shfl_down(ssp, off);
    c1p += __shfl_down(c1p, off);
    c2p += __shfl_down(c2p, off);
  }
  {
    const int lane = t & 63, wid = t >> 6;
    if (lane == 0) { rsm[wid * 3] = ssp; rsm[wid * 3 + 1] = c1p; rsm[wid * 3 + 2] = c2p; }
  }
  __syncthreads();

  // ---- P2/P4: stage1 over each half; P3: fold1(half 1) ----
#pragma unroll
  for (int h = 0; h < 2; ++h) {
    {  // stage1: thread = (n2' in 32) x (k3 in 8), rows A&B jointly
      const int n2p = t & 31, k3 = t >> 5;
      const int n2 = h * 32 + n2p;
      const float sg = (k3 & 1) ? -1.f : 1.f;
      float4 f0 = F1h[n2p];
      float reA = f0.x + sg * f0.y, imA = 0.f;
      float reB = f0.z + sg * f0.w, imB = 0.f;
      int jj = k3;
      for (int m = 1; m < 32; ++m) {
        float4 f4 = F1h[m * 32 + n2p];
        float2 tw = ct64[jj];
        reA += f4.x * tw.x; imA -= f4.y * tw.y;
        reB += f4.z * tw.x; imB -= f4.w * tw.y;
        jj = (jj + k3) & 63;
      }
      PL[k3 * 65 + n2] = reA;
      PL[(8 + k3) * 65 + n2] = imA;
      PL[(16 + k3) * 65 + n2] = reB;
      PL[(24 + k3) * 65 + n2] = imB;
    }
    if (h == 0) {
      if (t == 0) {
        red1p[((size_t)bc * 33 + j) * 3 + 0] = rsm[0] + rsm[3] + rsm[6] + rsm[9];
        red1p[((size_t)bc * 33 + j) * 3 + 1] = rsm[1] + rsm[4] + rsm[7] + rsm[10];
        red1p[((size_t)bc * 33 + j) * 3 + 2] = rsm[2] + rsm[5] + rsm[8] + rsm[11];
      }
      __syncthreads();   // stage1(0) reads of F1h done
      {  // fold1(half 1)
        const int n2p = t & 31, g = t >> 5;
        const int n2 = 32 + n2p;
#pragma unroll
        for (int e = 0; e < 4; ++e) {
          int m = g * 4 + e;
          if (m == 0) {
            F1h[n2p] = make_float4(Raw[n2 * 71], Raw[n2 * 71 + 32],
                                   Raw[(64 + n2) * 71], Raw[(64 + n2) * 71 + 32]);
          } else {
            float a1 = Raw[n2 * 71 + m], a2 = Raw[n2 * 71 + 64 - m];
            float b1 = Raw[(64 + n2) * 71 + m], b2 = Raw[(64 + n2) * 71 + 64 - m];
            F1h[m * 32 + n2p] = make_float4(a1 + a2, a1 - a2, b1 + b2, b1 - b2);
          }
        }
      }
      __syncthreads();   // F1h(half 1) ready
    }
  }
  __syncthreads();   // PL complete; F1h dead -> F2 may overwrite

  // ---- P5: fold2 (PL over n2) ----
  {
    const int rr = t & 31, g = t >> 5;
#pragma unroll
    for (int e = 0; e < 4; ++e) {
      int m = g * 4 + e;
      if (m == 0) {
        F2[rr] = make_float2(PL[rr * 65], PL[rr * 65 + 32]);
      } else {
        float p1 = PL[rr * 65 + m], p2 = PL[rr * 65 + 64 - m];
        F2[m * 32 + rr] = make_float2(p1 + p2, p1 - p2);
      }
    }
  }
  __syncthreads();

  // ---- P6: stage2 (n2->k2), thread = (rr in 32) x (k2 in 8) ----
  {
    const int rr = t & 31, k2 = t >> 5;
    const float sg = (k2 & 1) ? -1.f : 1.f;
    float2 e0 = F2[rr];
    float re = e0.x + sg * e0.y, im = 0.f;
    int jj = k2;
    for (int m = 1; m < 32; ++m) {
      float2 d = F2[m * 32 + rr];
      float2 tw = ct64[jj];
      re += d.x * tw.x;
      im -= d.y * tw.y;
      jj = (jj + k2) & 63;
    }
    const int row = rr >> 4, f = (rr >> 3) & 1, k3 = rr & 7;
    const int n1row = row ? n1b : n1a;
    ((float2*)S)[(((size_t)bc * 64 + n1row) * 2 + f) * 64 + k2 * 8 + k3] =
        make_float2(re, im);
  }
}

// ---------------- K2: stage3 (n1->k1) + corner r + normalize ----------------
// grid (2,128): h splits the k2k3 range; both f halves stay in-block for the combine.
__global__ __launch_bounds__(256) void k_fwd2s(const float* __restrict__ S,
                                               const float* __restrict__ red1p,
                                               float* __restrict__ xh) {
  __shared__ float2 U3L[512];     // [f][k1][kk&31]
  __shared__ float c64v[64], s64v[64];
  __shared__ float rbuf[99];
  const int t = threadIdx.x;
  const int h = blockIdx.x;       // 0..1
  const int bc = blockIdx.y;
  if (t < 64) { float ang = TWOPI_64 * t; c64v[t] = cosf(ang); s64v[t] = sinf(ang); }
  if (t < 99) rbuf[t] = red1p[(size_t)bc * 99 + t];
  __syncthreads();
  {
    const int kkl = t & 31;
    const int f = (t >> 5) & 1;
    const int k1g = t >> 6;            // 0..3, 2 k1 each
    const int rr2 = f * 64 + h * 32 + kkl;
    const float2* Sb = (const float2*)(S + ((size_t)bc << 14));
    float rc[2], rs[2], dc[2], ds[2], re[2], im[2];
#pragma unroll
    for (int m = 0; m < 2; ++m) {
      int k1 = k1g * 2 + m;
      rc[m] = 1.f; rs[m] = 0.f; dc[m] = c64v[k1]; ds[m] = s64v[k1];
      re[m] = 0.f; im[m] = 0.f;
    }
#pragma unroll 4
    for (int n1 = 0; n1 < 64; ++n1) {
      float2 ab = Sb[(n1 << 7) + rr2];
#pragma unroll
      for (int m = 0; m < 2; ++m) {
        re[m] += ab.x * rc[m] + ab.y * rs[m];
        im[m] += ab.y * rc[m] - ab.x * rs[m];
        float nc = rc[m] * dc[m] - rs[m] * ds[m];
        rs[m] = rs[m] * dc[m] + rc[m] * ds[m];
        rc[m] = nc;
      }
    }
#pragma unroll
    for (int m = 0; m < 2; ++m) {
      int k1 = k1g * 2 + m;
      U3L[f * 256 + k1 * 32 + kkl] = make_float2(re[m], im[m]);
    }
  }
  __syncthreads();
  float ss = 0.f, c1 = 0.f, c2 = 0.f;
  for (int jj = 0; jj < 33; ++jj) {
    ss += rbuf[jj * 3];
    c1 += rbuf[jj * 3 + 1];
    c2 += rbuf[jj * 3 + 2];
  }
  float nsq = 0.5f * (float)NT * (2.f * ss + c1 - c2);
  float inv1 = nsq > 0.f ? rsqrtf(nsq) : 0.f;
  {
    const int k1 = t >> 5, kkl = t & 31;
    const int kk = h * 32 + kkl;
    const int k3 = kk & 7;
    float2 U = U3L[k1 * 32 + kkl];
    float2 V = U3L[256 + k1 * 32 + kkl];
    float ct = c64v[k3], st = s64v[k3];
    float r = U.x - V.y - st * (U.x + V.y) - ct * (U.y - V.x);
    xh[(size_t)bc * 512 + k1 * 64 + kk] = r * inv1;
  }
}

// ---------------- K3: channel mixing + expansion stage A + second norm (fused) ----------------
__global__ __launch_bounds__(256) void k_mixA(const float* __restrict__ xh,
                                              const float* __restrict__ w,
                                              float* __restrict__ A1,
                                              float* __restrict__ inv2) {
  __shared__ float xsh[16384];   // exactly 64 KB; conv + tables reuse dead regions
  const int t = threadIdx.x;
  const int bc2 = blockIdx.x;
  const int b = bc2 >> 5, o = bc2 & 31;
  const float4* xb4 = (const float4*)(xh + ((size_t)b << 14));
  float4* xs4 = (float4*)xsh;
  for (int q = 0; q < 16; ++q) xs4[t + (q << 8)] = xb4[t + (q << 8)];
  __syncthreads();
  float acc0 = 0.f, acc1 = 0.f;
  {
    int k0 = t, kq1 = t + 256;
    int k1 = k0 >> 6, k2 = (k0 >> 3) & 7, k3 = k0 & 7;
    int nk0 = (((8 - k1) & 7) << 6) + (((8 - k2) & 7) << 3) + ((8 - k3) & 7);
    int l1 = kq1 >> 6, l2 = (kq1 >> 3) & 7, l3 = kq1 & 7;
    int nk1 = (((8 - l1) & 7) << 6) + (((8 - l2) & 7) << 3) + ((8 - l3) & 7);
    for (int i = 0; i < 32; ++i) {
      const float* wr = w + (((size_t)i * 32 + o) << 9);
      float xa0 = xsh[(i << 9) + k0],  xn0 = xsh[(i << 9) + nk0];
      float xa1 = xsh[(i << 9) + kq1], xn1 = xsh[(i << 9) + nk1];
      acc0 += (xa0 + xn0) * wr[k0]  + (xa0 - xn0) * wr[nk0];
      acc1 += (xa1 + xn1) * wr[kq1] + (xa1 - xn1) * wr[nk1];
    }
  }
  __syncthreads();               // all xsh reads done
  xsh[t] = 0.5f * acc0;          // conv -> xsh[0..511] (channel-0 region, dead)
  xsh[t + 256] = 0.5f * acc1;
  if (t < 64) {                  // twiddle tables -> xsh[512..639] (dead region)
    float ang = TWOPI_64 * t;
    xsh[512 + t] = cosf(ang);
    xsh[576 + t] = sinf(ang);
  }
  __syncthreads();
  const int col = t & 63;
  const int quarter = t >> 6;
  float cv[8];
#pragma unroll
  for (int n1 = 0; n1 < 8; ++n1) cv[n1] = xsh[(n1 << 6) + col];
  if (quarter == 0) {
    float p = 0.f;
#pragma unroll
    for (int n1 = 0; n1 < 8; ++n1) p += cv[n1] * cv[n1];
    for (int off = 32; off; off >>= 1) p += __shfl_down(p, off);
    if (t == 0) {
      float c000 = cv[0];
      float nsq = 0.5f * (float)NT * (2.f * p + c000 * c000);
      float nrm = sqrtf(nsq);
      inv2[bc2] = nrm > 0.f ? 1.f / (nrm * (float)NT) : 0.f;
    }
  }
  float2* A1p = (float2*)(A1 + ((size_t)bc2 << 13));
  for (int it = 0; it < 16; ++it) {
    int k1 = quarter + (it << 2);
    float re = 0.f, im = 0.f;
#pragma unroll
    for (int n1 = 0; n1 < 8; ++n1) {
      int a = (k1 * n1) & 63;
      re += cv[n1] * xsh[512 + a];
      im -= cv[n1] * xsh[576 + a];
    }
    A1p[(k1 << 6) + col] = make_float2(re, im);
  }
}

// ---------------- K4: expansion stages B+C fused; vector LDS reads ----------------
__global__ __launch_bounds__(256) void k_expBC(const float* __restrict__ A1,
                                               const float* __restrict__ inv2,
                                               float* __restrict__ out) {
  __shared__ float arow[128];
  __shared__ float B2[64 * 20];   // [k2][f*8+n3] pad 20: rows 16B-aligned, groups disjoint
  __shared__ float c64v[64], s64v[64];
  const int t = threadIdx.x;
  const int k1 = blockIdx.x;
  const int bc2 = blockIdx.y;
  if (t < 64) { float ang = TWOPI_64 * t; c64v[t] = cosf(ang); s64v[t] = sinf(ang); }
  if (t < 128) arow[t] = A1[((size_t)bc2 << 13) + (k1 << 7) + t];
  __syncthreads();
  {  // stage B: contract n2 for all 64 k2; thread = (k2, f, n3-quad); g wave-uniform
    const int k2 = t & 63;
    const int g = t >> 6;
    const int f = g & 1;
    const int n3h = (g >> 1) << 2;
    float acc[4] = {0, 0, 0, 0};
    for (int n2i = 0; n2i < 8; ++n2i) {
      int a_ = (k2 * n2i) & 63;
      float tc = c64v[a_], ts = s64v[a_];
      const float4* ar4 = (const float4*)&arow[((n2i << 3) + n3h) << 1];
      float4 p0 = ar4[0];   // a0,b0,a1,b1  (uniform -> broadcast b128)
      float4 p1 = ar4[1];   // a2,b2,a3,b3
      if (f == 0) {
        acc[0] += p0.x * tc + p0.y * ts;
        acc[1] += p0.z * tc + p0.w * ts;
        acc[2] += p1.x * tc + p1.y * ts;
        acc[3] += p1.z * tc + p1.w * ts;
      } else {
        acc[0] += p0.y * tc - p0.x * ts;
        acc[1] += p0.w * tc - p0.z * ts;
        acc[2] += p1.y * tc - p1.x * ts;
        acc[3] += p1.w * tc - p1.z * ts;
      }
    }
    *(float4*)&B2[k2 * 20 + (f << 3) + n3h] = make_float4(acc[0], acc[1], acc[2], acc[3]);
  }
  __syncthreads();
  {  // stage C: contract n3 for all k3 with fused flip coefficients; b128 row reads
    const int k3 = t & 63;
    const int wid = t >> 6;
    float C1r[8], C2r[8];
#pragma unroll
    for (int n3 = 0; n3 < 8; ++n3) {
      int a0 = (k3 * n3) & 63;
      int a1 = (k3 * (n3 + 1)) & 63;
      C1r[n3] = c64v[a0] - s64v[a1];
      C2r[n3] = s64v[a0] - c64v[a1];
    }
    const float sc = inv2[bc2];
    float* dst = out + ((size_t)bc2 << 18) + (k1 << 12);
    for (int it = 0; it < 16; ++it) {
      int k2 = (wid << 4) + it;
      const float4* br4 = (const float4*)&B2[k2 * 20];   // uniform -> broadcast b128
      float4 r0 = br4[0], r1 = br4[1], r2 = br4[2], r3 = br4[3];
      float acc = r0.x * C1r[0] + r0.y * C1r[1] + r0.z * C1r[2] + r0.w * C1r[3]
                + r1.x * C1r[4] + r1.y * C1r[5] + r1.z * C1r[6] + r1.w * C1r[7]
                + r2.x * C2r[0] + r2.y * C2r[1] + r2.z * C2r[2] + r2.w * C2r[3]
                + r3.x * C2r[4] + r3.y * C2r[5] + r3.z * C2r[6] + r3.w * C2r[7];
      dst[(k2 << 6) + k3] = acc * sc;
    }
  }
}

extern "C" void kernel_launch(void* const* d_in, const int* in_sizes, int n_in,
                              void* d_out, int out_size, void* d_ws, size_t ws_size,
                              hipStream_t stream) {
  const float* x = (const float*)d_in[0];
  const float* w = (const float*)d_in[1];
  float* out = (float*)d_out;
  float* ws = (float*)d_ws;
  float* S     = ws;
  float* red1p = ws + 2097152;
  float* xh    = ws + 2109824;
  float* inv2  = ws + 2175360;
  float* A1    = ws + 2175488;

  k_fwd1 <<<dim3(33, 128), 256, 0, stream>>>(x, S, red1p);
  k_fwd2s<<<dim3(2, 128),  256, 0, stream>>>(S, red1p, xh);
  k_mixA <<<dim3(128),     256, 0, stream>>>(xh, w, A1, inv2);
  k_expBC<<<dim3(64, 128), 256, 0, stream>>>(A1, inv2, out);
}